// Round 7
// baseline (100.182 us; speedup 1.0000x reference)
//
#include <hip/hip_runtime.h>

#define BB 2
#define LL 16
#define CC 16
#define HH 64
#define WW 64
#define HWSZ (HH * WW)
#define NSEG 36   // per i: ceil(i/4) j-segments (exact widths 1..4), i = 1..15

__device__ __constant__ int SEG_I[NSEG] = {
    1, 2, 3, 4,
    5, 5, 6, 6, 7, 7, 8, 8,
    9, 9, 9, 10, 10, 10, 11, 11, 11, 12, 12, 12,
    13, 13, 13, 13, 14, 14, 14, 14, 15, 15, 15, 15};
__device__ __constant__ int SEG_J0[NSEG] = {
    0, 0, 0, 0,
    0, 4, 0, 4, 0, 4, 0, 4,
    0, 4, 8, 0, 4, 8, 0, 4, 8, 0, 4, 8,
    0, 4, 8, 12, 0, 4, 8, 12, 0, 4, 8, 12};

// ws layout: [0, 1MB) cum2 as (B, L, HW) float2;
//            [1MB, 9MB) quad-planar images: qp[((bl*4 + qs)*HWSZ + pix)] = float4 of
//            channels qs*4 .. qs*4+3 at pixel pix.
#define CUM2_FLOATS (BB * LL * HWSZ * 2)   // 262144

// ---- Fused prep kernel ----
// blocks [0,32):        cumsum of flows -> cum2 (float2-interleaved)
// blocks [32, 32+2048): NCHW -> quad-planar transpose AND identity-term write to out
__global__ __launch_bounds__(256) void gsp_prep(
    const float* __restrict__ flows,   // (B, L, 2, H, W)
    const float* __restrict__ images,  // (B, L, C, H, W)
    float2* __restrict__ cum2,         // (B, L, HW) float2
    float4* __restrict__ qp,           // (B*L, 4, HW) float4 quad-planes
    float* __restrict__ out)           // (B, L, C, H, W)
{
    if (blockIdx.x < 32) {
        const int gid = blockIdx.x * 256 + threadIdx.x;   // 0..8191
        const int b   = gid >> 12;
        const int pix = gid & (HWSZ - 1);
        const float* fb = flows + (size_t)b * LL * 2 * HWSZ + pix;
        float vx[LL], vy[LL];
        #pragma unroll
        for (int l = 0; l < LL; ++l) {
            vx[l] = fb[(size_t)l * 2 * HWSZ];
            vy[l] = fb[(size_t)l * 2 * HWSZ + HWSZ];
        }
        #pragma unroll
        for (int l = 1; l < LL; ++l) { vx[l] += vx[l - 1]; vy[l] += vy[l - 1]; }
        float2* cb = cum2 + (size_t)b * LL * HWSZ + pix;
        #pragma unroll
        for (int l = 0; l < LL; ++l) {
            float2 v; v.x = vx[l]; v.y = vy[l];
            cb[(size_t)l * HWSZ] = v;
        }
    } else {
        const int gid  = (blockIdx.x - 32) * 256 + threadIdx.x;  // 0..524287
        const int quad = gid & 3;
        const int pix  = (gid >> 2) & (HWSZ - 1);
        const int bl   = gid >> 14;

        const float* src = images + (size_t)(bl * CC + quad * 4) * HWSZ + pix;
        float4 v;
        v.x = src[0 * HWSZ];
        v.y = src[1 * HWSZ];
        v.z = src[2 * HWSZ];
        v.w = src[3 * HWSZ];
        qp[((size_t)bl * 4 + quad) * HWSZ + pix] = v;

        // identity term (j == i samples land exactly on integer pixel centers)
        float* op = out + (size_t)(bl * CC + quad * 4) * HWSZ + pix;
        op[0 * HWSZ] = v.x;
        op[1 * HWSZ] = v.y;
        op[2 * HWSZ] = v.z;
        op[3 * HWSZ] = v.w;
    }
}

// ---- Segment kernel: block = (b, seg, qs). For each j in the segment, stage the
//      full (b, j, qs) 4-channel plane (64 KB) in LDS, then gather bilinear corners
//      with ds_read_b128 (LDS serves all 64 lanes in parallel -> kills the VMEM
//      per-lane-request wall). Accumulate over the segment, one atomic commit. ----
__global__ __launch_bounds__(1024, 8) void gsp_seg(
    const float2* __restrict__ cum2,   // (B, L, HW) float2
    const float4* __restrict__ qp,     // (B*L, 4, HW) float4 quad-planes
    float* __restrict__ out)           // (B, L, C, H, W)
{
    __shared__ float4 tile[HWSZ];      // 64 KB — exactly one plane

    const int qs  = blockIdx.x & 3;
    const int seg = (blockIdx.x >> 2) % NSEG;
    const int b   = blockIdx.x / (4 * NSEG);

    const int i  = SEG_I[seg];
    const int j0 = SEG_J0[seg];
    const int j1 = min(j0 + 3, i - 1);

    const float2* cum_b = cum2 + (size_t)b * LL * HWSZ;

    // per-thread pixels: threadIdx.x + it*1024, it = 0..3
    float2 ci[4];
    float4 acc[4];
    #pragma unroll
    for (int it = 0; it < 4; ++it) {
        const int px = threadIdx.x + it * 1024;
        ci[it] = cum_b[(size_t)i * HWSZ + px];
        acc[it].x = 0.0f; acc[it].y = 0.0f; acc[it].z = 0.0f; acc[it].w = 0.0f;
    }

    for (int j = j0; j <= j1; ++j) {
        // stage plane (b, j, qs): contiguous 64 KB, coalesced
        const float4* src = qp + ((size_t)(b * LL + j) * 4 + qs) * HWSZ;
        #pragma unroll
        for (int it = 0; it < 4; ++it)
            tile[it * 1024 + threadIdx.x] = src[it * 1024 + threadIdx.x];
        __syncthreads();

        #pragma unroll
        for (int it = 0; it < 4; ++it) {
            const int px = threadIdx.x + it * 1024;
            const int h = px >> 6;
            const int w = px & (WW - 1);

            const float2 cj = cum_b[(size_t)j * HWSZ + px];

            float gx = (w + 0.5f) * (2.0f / WW) - 1.0f + (ci[it].x - cj.x);
            float gy = (h + 0.5f) * (2.0f / HH) - 1.0f + (ci[it].y - cj.y);

            // gx = remainder(gx + 1, 2) - 1
            float tt = gx + 1.0f;
            tt = tt - floorf(tt * 0.5f) * 2.0f;
            gx = tt - 1.0f;

            const float ix = ((gx + 1.0f) * WW - 1.0f) * 0.5f;
            const float iy = ((gy + 1.0f) * HH - 1.0f) * 0.5f;
            const float x0f = floorf(ix);
            const float y0f = floorf(iy);
            const float fx = ix - x0f;
            const float fy = iy - y0f;
            const int x0 = (int)x0f;
            const int y0 = (int)y0f;
            const int x1 = x0 + 1;
            const int y1 = y0 + 1;

            const bool vx0 = (x0 >= 0) && (x0 < WW);
            const bool vx1 = (x1 >= 0) && (x1 < WW);
            const bool vy0 = (y0 >= 0) && (y0 < HH);
            const bool vy1 = (y1 >= 0) && (y1 < HH);

            const int cx0 = min(max(x0, 0), WW - 1);
            const int cx1 = min(max(x1, 0), WW - 1);
            const int cy0 = min(max(y0, 0), HH - 1);
            const int cy1 = min(max(y1, 0), HH - 1);

            const float w00 = ((vx0 && vy0) ? 1.0f : 0.0f) * (1.0f - fx) * (1.0f - fy);
            const float w01 = ((vx1 && vy0) ? 1.0f : 0.0f) * fx * (1.0f - fy);
            const float w10 = ((vx0 && vy1) ? 1.0f : 0.0f) * (1.0f - fx) * fy;
            const float w11 = ((vx1 && vy1) ? 1.0f : 0.0f) * fx * fy;

            const float4 v00 = tile[cy0 * WW + cx0];
            const float4 v01 = tile[cy0 * WW + cx1];
            const float4 v10 = tile[cy1 * WW + cx0];
            const float4 v11 = tile[cy1 * WW + cx1];

            acc[it].x += w00 * v00.x + w01 * v01.x + w10 * v10.x + w11 * v11.x;
            acc[it].y += w00 * v00.y + w01 * v01.y + w10 * v10.y + w11 * v11.y;
            acc[it].z += w00 * v00.z + w01 * v01.z + w10 * v10.z + w11 * v11.z;
            acc[it].w += w00 * v00.w + w01 * v01.w + w10 * v10.w + w11 * v11.w;
        }
        __syncthreads();
    }

    float* op = out + ((size_t)(b * LL + i) * CC + qs * 4) * HWSZ;
    #pragma unroll
    for (int it = 0; it < 4; ++it) {
        const int px = threadIdx.x + it * 1024;
        atomicAdd(op + 0 * HWSZ + px, acc[it].x);
        atomicAdd(op + 1 * HWSZ + px, acc[it].y);
        atomicAdd(op + 2 * HWSZ + px, acc[it].z);
        atomicAdd(op + 3 * HWSZ + px, acc[it].w);
    }
}

extern "C" void kernel_launch(void* const* d_in, const int* in_sizes, int n_in,
                              void* d_out, int out_size, void* d_ws, size_t ws_size,
                              hipStream_t stream) {
    const float* flows  = (const float*)d_in[0];
    const float* images = (const float*)d_in[1];
    float* out = (float*)d_out;
    float2* cum2 = (float2*)d_ws;                       // 1 MB
    float*  qp   = (float*)d_ws + CUM2_FLOATS;          // 8 MB quad-planar

    gsp_prep<<<32 + 2048, 256, 0, stream>>>(flows, images, cum2, (float4*)qp, out);

    const int grid = BB * NSEG * 4;                     // 288 blocks x 1024 threads
    gsp_seg<<<grid, 1024, 0, stream>>>(cum2, (const float4*)qp, out);
}